// Round 7
// baseline (247.863 us; speedup 1.0000x reference)
//
#include <hip/hip_runtime.h>
#include <stdint.h>
#include <stddef.h>

// ---------------------------------------------------------------------------
// MultiHeadAttentionBlock: B=4, C=2048, D=1024, H=8, K=64, V=128
//
//   q_{b,g}[r][k]  = Pq[b*2048 + g*256 + r/8][(r%8)*64 + k]   (contiguous [2048,64])
//   v_{b,h}[c2][d] = Pv[b][h*256 + c2/8][(c2%8)*128 + d]
//   out[b, c, h, d] = sum_c2 att_{b,g=c/256}[r=(c%256)*8+h][c2] * v_{b,h}[c2][d]
//   att[r][c2] = exp(s[r][c2]/8) / sum_r' exp(s[r'][c2]/8)    (softmax over r)
//
// R7 = R6 minus the broken k_gemm v-transpose epilogue (head index comes from
// the ROW block, not the column block -> direct write is stride-8 scattered;
// reverted to the known-correct k_T transpose kernel + linear pv store).
// Kept from R6:
//  * pass2 staging via global_load_lds, swizzle folded into the GLOBAL chunk
//    index (DMA LDS dest is lane-linear). kss slot=(c+(r>>3)+2*(r&3))&7,
//    vs slot=(c+d)&7 -> conflict-free permuted-A and PV reads.
//  * bf16 pack via v_perm (round-half-up, 0.75 VALU/elem).
//  * q B-frags read once from global; P register-direct into PV B-frags.
//  * Pq pre-scaled by 0.125 in k_gemm epilogue (exact, power of two).
// ---------------------------------------------------------------------------

typedef short     bf8v  __attribute__((ext_vector_type(8)));   // 8 x bf16 (x32 A/B frag)
typedef float     f4v   __attribute__((ext_vector_type(4)));   // 4 x f32 (C/D frag)
typedef unsigned short u16x4 __attribute__((ext_vector_type(4)));
typedef unsigned short u16x8 __attribute__((ext_vector_type(8)));
typedef unsigned int   u32x4 __attribute__((ext_vector_type(4)));

// pack two f32 -> two bf16 (round-half-up; <=0.5ulp diff vs RNE at ties only)
__device__ __forceinline__ unsigned int pk2(float a, float b) {
    union { float f; uint32_t u; } x, y; x.f = a; y.f = b;
    return __builtin_amdgcn_perm(y.u + 0x8000u, x.u + 0x8000u, 0x07060302u);
}

#define MFMA32(A, B, C) __builtin_amdgcn_mfma_f32_16x16x32_bf16((A), (B), (C), 0, 0, 0)
#define ASYNC16(g, l) __builtin_amdgcn_global_load_lds(                        \
    (const __attribute__((address_space(1))) unsigned int*)(g),                \
    (__attribute__((address_space(3))) unsigned int*)(l), 16, 0, 0)

// -------------------- fp32 -> bf16 elementwise convert ----------------------
__global__ __launch_bounds__(256) void k_cvt(const float* __restrict__ in,
                                             unsigned short* __restrict__ out, int n4) {
    int i = blockIdx.x * 256 + threadIdx.x;
    if (i >= n4) return;
    f4v v = *(const f4v*)(in + (size_t)i * 4);
    uint2 o; o.x = pk2(v[0], v[1]); o.y = pk2(v[2], v[3]);
    *(uint2*)(out + (size_t)i * 4) = o;
}

// ---- fp32 [1024][N] -> bf16 transposed [N][1024], all 3 weights fused ------
__global__ __launch_bounds__(256) void k_cvtT3(const float* __restrict__ Mq,
                                               const float* __restrict__ Mk,
                                               const float* __restrict__ Mv,
                                               unsigned short* __restrict__ wqt,
                                               unsigned short* __restrict__ wkt,
                                               unsigned short* __restrict__ wvt) {
    __shared__ unsigned short t[64][68];
    const int tid = threadIdx.x;
    const int tr = tid >> 4, tc4 = (tid & 15) * 4;
    const float* in; unsigned short* outT; int Ncols, cb;
    if (blockIdx.z == 0) {
        if (blockIdx.x < 8) { in = Mq; outT = wqt; Ncols = 512; cb = blockIdx.x * 64; }
        else                { in = Mk; outT = wkt; Ncols = 512; cb = (blockIdx.x - 8) * 64; }
    } else                  { in = Mv; outT = wvt; Ncols = 1024; cb = blockIdx.x * 64; }
    const int rb = blockIdx.y * 64;
#pragma unroll
    for (int p = 0; p < 4; ++p) {
        int r = tr + p * 16;
        f4v v = *(const f4v*)(in + (size_t)(rb + r) * Ncols + cb + tc4);
        *(unsigned int*)&t[r][tc4]     = pk2(v[0], v[1]);
        *(unsigned int*)&t[r][tc4 + 2] = pk2(v[2], v[3]);
    }
    __syncthreads();
#pragma unroll
    for (int p = 0; p < 4; ++p) {
        int r = tr + p * 16;               // output row = input col cb + r
        u16x4 o;
        o[0] = t[tc4 + 0][r]; o[1] = t[tc4 + 1][r];
        o[2] = t[tc4 + 2][r]; o[3] = t[tc4 + 3][r];
        *(u16x4*)(outT + (size_t)(cb + r) * 1024 + rb + tc4) = o;
    }
}

// -------- bf16 transpose [2048][128] -> [128][2048], 32 batches (b,h) -------
__global__ __launch_bounds__(256) void k_T(const unsigned short* __restrict__ in,
                                           unsigned short* __restrict__ out) {
    __shared__ unsigned short t[64][68];
    const int tid = threadIdx.x;
    const int tr = tid >> 4, tc4 = (tid & 15) * 4;
    const int rb = blockIdx.y * 64, cb = blockIdx.x * 64;
    const unsigned short* ib = in  + (size_t)blockIdx.z * 262144;
    unsigned short*       ob = out + (size_t)blockIdx.z * 262144;
#pragma unroll
    for (int p = 0; p < 4; ++p) {
        int r = tr + p * 16;
        u16x4 v = *(const u16x4*)(ib + (size_t)(rb + r) * 128 + cb + tc4);
        t[r][tc4 + 0] = v[0]; t[r][tc4 + 1] = v[1];
        t[r][tc4 + 2] = v[2]; t[r][tc4 + 3] = v[3];
    }
    __syncthreads();
#pragma unroll
    for (int p = 0; p < 4; ++p) {
        int r = tr + p * 16;
        u16x4 o;
        o[0] = t[tc4 + 0][r]; o[1] = t[tc4 + 1][r];
        o[2] = t[tc4 + 2][r]; o[3] = t[tc4 + 3][r];
        *(u16x4*)(ob + (size_t)(cb + r) * 2048 + rb + tc4) = o;
    }
}

// ------- fused projection GEMM: {Pq,Pk,Pv} = Xb[8192][1024] @ {Mq,Mk,Mv} ----
// Wt = [2048][1024] stacked. global_load_lds dbuf staging, XOR-swizzled tiles.
__global__ __launch_bounds__(256, 2) void k_gemm(const unsigned short* __restrict__ X,
                                                 const unsigned short* __restrict__ Wt,
                                                 unsigned short* __restrict__ pq,
                                                 unsigned short* __restrict__ pk,
                                                 unsigned short* __restrict__ pv) {
    __shared__ __align__(16) unsigned short smem[32768];   // xs[2][8192] | ws[2][8192]
    const int tid = threadIdx.x;
    const int lane = tid & 63, w = tid >> 6;
    const int lc = lane & 15, quad = lane >> 4;
    const int rowb = blockIdx.x * 128, cb = blockIdx.y;

    unsigned short* outp; int N, colb; float scale;
    if (cb < 4)      { outp = pq; N = 512;  colb = cb * 128;       scale = 0.125f; }
    else if (cb < 8) { outp = pk; N = 512;  colb = (cb - 4) * 128; scale = 1.0f; }
    else             { outp = pv; N = 1024; colb = (cb - 8) * 128; scale = 1.0f; }

    const int lr   = lane >> 3;                 // 0..7
    const int swz  = ((lane & 7) ^ lr) * 8;     // swizzled chunk -> elem offset

    f4v acc[2][8];
#pragma unroll
    for (int mt = 0; mt < 2; ++mt)
#pragma unroll
        for (int nt = 0; nt < 8; ++nt) acc[mt][nt] = f4v{0.f, 0.f, 0.f, 0.f};

    // prologue: stage chunk 0 into buf 0
#pragma unroll
    for (int j = 0; j < 4; ++j) {
        int row = (w * 4 + j) * 8 + lr;
        ASYNC16(X  + (size_t)(rowb + row) * 1024 + swz,     &smem[(w * 4 + j) * 512]);
        ASYNC16(Wt + (size_t)(cb * 128 + row) * 1024 + swz, &smem[16384 + (w * 4 + j) * 512]);
    }
    __syncthreads();

    for (int k = 0; k < 16; ++k) {
        const int buf = k & 1;
        const int xoff = buf * 8192, woff = 16384 + buf * 8192;
        if (k < 15) {
            const int k0n = (k + 1) * 64;
            const int nx = (buf ^ 1) * 8192, nw = 16384 + (buf ^ 1) * 8192;
#pragma unroll
            for (int j = 0; j < 4; ++j) {
                int row = (w * 4 + j) * 8 + lr;
                ASYNC16(X  + (size_t)(rowb + row) * 1024 + k0n + swz,     &smem[nx + (w * 4 + j) * 512]);
                ASYNC16(Wt + (size_t)(cb * 128 + row) * 1024 + k0n + swz, &smem[nw + (w * 4 + j) * 512]);
            }
        }
#pragma unroll
        for (int ks = 0; ks < 2; ++ks) {
            bf8v bx[8];
#pragma unroll
            for (int nt = 0; nt < 8; ++nt) {
                int row = nt * 16 + lc;
                int c8  = (ks * 4 + quad) ^ (lc & 7);
                bx[nt] = *(const bf8v*)(&smem[xoff + row * 64 + c8 * 8]);
            }
#pragma unroll
            for (int mt = 0; mt < 2; ++mt) {
                int row = w * 32 + mt * 16 + lc;
                int c8  = (ks * 4 + quad) ^ (lc & 7);
                bf8v a = *(const bf8v*)(&smem[woff + row * 64 + c8 * 8]);
#pragma unroll
                for (int nt = 0; nt < 8; ++nt) acc[mt][nt] = MFMA32(a, bx[nt], acc[mt][nt]);
            }
        }
        __syncthreads();
    }
    // C^T store: 4 regs = 4 consecutive output cols
#pragma unroll
    for (int mt = 0; mt < 2; ++mt)
#pragma unroll
        for (int nt = 0; nt < 8; ++nt) {
            int crow = rowb + nt * 16 + lc;
            int ccol = colb + w * 32 + mt * 16 + quad * 4;
            uint2 o;
            o.x = pk2(acc[mt][nt][0] * scale, acc[mt][nt][1] * scale);
            o.y = pk2(acc[mt][nt][2] * scale, acc[mt][nt][3] * scale);
            *(uint2*)(outp + (size_t)crow * N + ccol) = o;
        }
}

// ------ pass 1: rdenl[bg][c2] = -ln( sum_r exp(q_r . k_c2) )  (q pre-scaled)
__global__ __launch_bounds__(256, 2) void k_pass1(const unsigned short* __restrict__ Pq,
                                                  const unsigned short* __restrict__ Pk,
                                                  float* __restrict__ rdenl) {
    __shared__ __align__(16) unsigned short kls[8192];      // k tile [128][64] swizzled
    __shared__ __align__(16) unsigned short qls[2][8192];   // q dbuf  [128][64] swizzled
    __shared__ float dsum[4][128];
    const int tid = threadIdx.x;
    const int lane = tid & 63, w = tid >> 6;
    const int lc = lane & 15, quad = lane >> 4;
    const int c2b = blockIdx.x * 128;
    const int bg  = blockIdx.y;
    const unsigned short* qbase = Pq + (size_t)bg * 131072;
    const unsigned short* kbase = Pk + (size_t)bg * 131072 + (size_t)c2b * 64;

    const int lr  = lane >> 3;
    const int swz = ((lane & 7) ^ lr) * 8;

    // prologue: k tile (once) + q tile 0 into buf 0
#pragma unroll
    for (int j = 0; j < 4; ++j) {
        int row = (w * 4 + j) * 8 + lr;
        ASYNC16(kbase + (size_t)row * 64 + swz, &kls[(w * 4 + j) * 512]);
        ASYNC16(qbase + (size_t)row * 64 + swz, &qls[0][(w * 4 + j) * 512]);
    }
    __syncthreads();

    float csum[8];
#pragma unroll
    for (int nt = 0; nt < 8; ++nt) csum[nt] = 0.f;

    for (int it = 0; it < 16; ++it) {
        const int buf = it & 1;
        if (it < 15) {
            const unsigned short* qn = qbase + (size_t)(it + 1) * 8192;
#pragma unroll
            for (int j = 0; j < 4; ++j) {
                int row = (w * 4 + j) * 8 + lr;
                ASYNC16(qn + (size_t)row * 64 + swz, &qls[buf ^ 1][(w * 4 + j) * 512]);
            }
        }

        f4v sc[2][8];
#pragma unroll
        for (int mt = 0; mt < 2; ++mt)
#pragma unroll
            for (int nt = 0; nt < 8; ++nt) sc[mt][nt] = f4v{0.f, 0.f, 0.f, 0.f};
#pragma unroll
        for (int ks = 0; ks < 2; ++ks) {
            bf8v bk[8];
#pragma unroll
            for (int nt = 0; nt < 8; ++nt) {
                int row = nt * 16 + lc;
                int c8  = (ks * 4 + quad) ^ (lc & 7);
                bk[nt] = *(const bf8v*)(&kls[row * 64 + c8 * 8]);
            }
#pragma unroll
            for (int mt = 0; mt < 2; ++mt) {
                int row = w * 32 + mt * 16 + lc;
                int c8  = (ks * 4 + quad) ^ (lc & 7);
                bf8v a = *(const bf8v*)(&qls[buf][row * 64 + c8 * 8]);
#pragma unroll
                for (int nt = 0; nt < 8; ++nt) sc[mt][nt] = MFMA32(a, bk[nt], sc[mt][nt]);
            }
        }
#pragma unroll
        for (int mt = 0; mt < 2; ++mt)
#pragma unroll
            for (int nt = 0; nt < 8; ++nt)
#pragma unroll
                for (int r = 0; r < 4; ++r)
                    csum[nt] += __expf(sc[mt][nt][r]);   // q pre-scaled by 1/8
        __syncthreads();
    }

#pragma unroll
    for (int nt = 0; nt < 8; ++nt) {   // reduce across quads (rows live in regs+quads)
        float v = csum[nt];
        v += __shfl_xor(v, 16, 64);
        v += __shfl_xor(v, 32, 64);
        if (quad == 0) dsum[w][nt * 16 + lc] = v;
    }
    __syncthreads();
    if (tid < 128) {
        float tot = dsum[0][tid] + dsum[1][tid] + dsum[2][tid] + dsum[3][tid];
        rdenl[(size_t)bg * 2048 + c2b + tid] = -__logf(tot);
    }
}

// --------- pass 2: out[b, g*256+j, h, :] = P_{bg}[j*8+h, :] @ v_{b,h} -------
// S^T permuted-A -> exp -> x32 B-frag (register-direct P). ASYNC16 dbuf staging.
__global__ __launch_bounds__(256, 2) void k_pass2(const unsigned short* __restrict__ Pq,
                                                  const unsigned short* __restrict__ Pk,
                                                  const unsigned short* __restrict__ Vt,
                                                  const float* __restrict__ rdenl,
                                                  float* __restrict__ out) {
    __shared__ __align__(16) unsigned short kss[2][4096];   // [c2 64][64] swizzled
    __shared__ __align__(16) unsigned short vs[2][8192];    // [d 128][c2 64] swizzled
    const int tid = threadIdx.x;
    const int lane = tid & 63, w = tid >> 6;
    const int lc = lane & 15, quad = lane >> 4;
    const int jt = blockIdx.x, h = blockIdx.y, bg = blockIdx.z;
    const int b = bg >> 3, g = bg & 7;

    const unsigned short* qbase = Pq + (size_t)bg * 131072;
    const unsigned short* kbase = Pk + (size_t)bg * 131072;
    const unsigned short* vbase = Vt + (size_t)(b * 8 + h) * 262144;
    const float* rdl = rdenl + (size_t)bg * 2048;

    // q B-frags straight from global (one-time, L2/L3-resident)
    bf8v bq[2][2];
#pragma unroll
    for (int nt = 0; nt < 2; ++nt)
#pragma unroll
        for (int ks = 0; ks < 2; ++ks)
            bq[nt][ks] = *(const bf8v*)(qbase +
                (size_t)((jt * 128 + w * 32 + nt * 16 + lc) * 8 + h) * 64 + ks * 32 + quad * 8);

    const int l3 = lane >> 3, l7 = lane & 7;
    // prologue: chunk 0 -> buf 0.  kss slot=(c+(r>>3)+2*(r&3))&7; vs slot=(c+d)&7
#pragma unroll
    for (int j = 0; j < 2; ++j) {
        int seg = w * 2 + j;
        int r   = seg * 8 + l3;
        int c   = (l7 - seg - 2 * (l3 & 3)) & 7;
        ASYNC16(kbase + (size_t)r * 64 + c * 8, &kss[0][seg * 512]);
    }
#pragma unroll
    for (int j = 0; j < 4; ++j) {
        int seg = w * 4 + j;
        int d   = seg * 8 + l3;
        int c   = (l7 - l3) & 7;
        ASYNC16(vbase + (size_t)d * 2048 + c * 8, &vs[0][seg * 512]);
    }
    __syncthreads();

    f4v acc[8][2];
#pragma unroll
    for (int dt = 0; dt < 8; ++dt)
#pragma unroll
        for (int nt = 0; nt < 2; ++nt) acc[dt][nt] = f4v{0.f, 0.f, 0.f, 0.f};

    for (int cc = 0; cc < 32; ++cc) {
        const int buf = cc & 1;
        if (cc < 31) {
            const int c2n = (cc + 1) * 64;
#pragma unroll
            for (int j = 0; j < 2; ++j) {
                int seg = w * 2 + j;
                int r   = seg * 8 + l3;
                int c   = (l7 - seg - 2 * (l3 & 3)) & 7;
                ASYNC16(kbase + (size_t)(c2n + r) * 64 + c * 8, &kss[buf ^ 1][seg * 512]);
            }
#pragma unroll
            for (int j = 0; j < 4; ++j) {
                int seg = w * 4 + j;
                int d   = seg * 8 + l3;
                int c   = (l7 - l3) & 7;
                ASYNC16(vbase + (size_t)d * 2048 + c2n + c * 8, &vs[buf ^ 1][seg * 512]);
            }
        }

        // S^T, permuted A rows: sc[mt](quad,reg) holds c2 = (mt>>1)*32+quad*8+(mt&1)*4+reg
        f4v sc[4][2];
#pragma unroll
        for (int mt = 0; mt < 4; ++mt)
#pragma unroll
            for (int nt = 0; nt < 2; ++nt) sc[mt][nt] = f4v{0.f, 0.f, 0.f, 0.f};
#pragma unroll
        for (int ks = 0; ks < 2; ++ks) {
            bf8v a[4];
#pragma unroll
            for (int mt = 0; mt < 4; ++mt) {
                int rlog = ((mt >> 1) << 5) + ((lc >> 2) << 3) + ((mt & 1) << 2) + (lc & 3);
                int slot = (ks * 4 + quad + ((mt >> 1) << 2) + (lc >> 2) + 2 * (lc & 3)) & 7;
                a[mt] = *(const bf8v*)(&kss[buf][rlog * 64 + slot * 8]);
            }
#pragma unroll
            for (int mt = 0; mt < 4; ++mt)
#pragma unroll
                for (int nt = 0; nt < 2; ++nt)
                    sc[mt][nt] = MFMA32(a[mt], bq[nt][ks], sc[mt][nt]);
        }

        // P^T = exp(S^T + lrd), pair-packed via v_perm into x32 B-frags
        u32x4 pb[2][2];
#pragma unroll
        for (int mt = 0; mt < 4; ++mt) {
            f4v lrd = *(const f4v*)(rdl + cc * 64 + ((mt >> 1) << 5) + (quad << 3) + ((mt & 1) << 2));
#pragma unroll
            for (int nt = 0; nt < 2; ++nt) {
                float e0 = __expf(sc[mt][nt][0] + lrd[0]);
                float e1 = __expf(sc[mt][nt][1] + lrd[1]);
                float e2 = __expf(sc[mt][nt][2] + lrd[2]);
                float e3 = __expf(sc[mt][nt][3] + lrd[3]);
                pb[mt >> 1][nt][(mt & 1) * 2 + 0] = pk2(e0, e1);
                pb[mt >> 1][nt][(mt & 1) * 2 + 1] = pk2(e2, e3);
            }
        }

        // PV: Out^T[d][r] += v^T[d][c2] @ P^T[c2][r]
#pragma unroll
        for (int kc = 0; kc < 2; ++kc)
#pragma unroll
            for (int dt = 0; dt < 8; ++dt) {
                int dd = dt * 16 + lc;
                int slot = (kc * 4 + quad + (lc & 7)) & 7;
                bf8v a = *(const bf8v*)(&vs[buf][dd * 64 + slot * 8]);
#pragma unroll
                for (int nt = 0; nt < 2; ++nt)
                    acc[dt][nt] = MFMA32(a, *(const bf8v*)&pb[kc][nt], acc[dt][nt]);
            }
        __syncthreads();
    }

    // epilogue: d = dt*16+quad*4+reg (4 consecutive), r = w*32+nt*16+lc
    float* ob = out + (size_t)(b * 2048 + g * 256 + jt * 128) * 1024 + h * 128;
#pragma unroll
    for (int dt = 0; dt < 8; ++dt)
#pragma unroll
        for (int nt = 0; nt < 2; ++nt) {
            int r = w * 32 + nt * 16 + lc;
            int d = dt * 16 + quad * 4;
            *(f4v*)(ob + (size_t)r * 1024 + d) = acc[dt][nt];
        }
}

// ---------------------------------------------------------------------------
extern "C" void kernel_launch(void* const* d_in, const int* in_sizes, int n_in,
                              void* d_out, int out_size, void* d_ws, size_t ws_size,
                              hipStream_t stream) {
    const float* x  = (const float*)d_in[0];   // [4][2048][1024]
    const float* Mq = (const float*)d_in[1];   // [1024][512]
    const float* Mk = (const float*)d_in[2];   // [1024][512]
    const float* Mv = (const float*)d_in[3];   // [1024][1024]
    float* out = (float*)d_out;                // [4][2048][1024]

    char* base = (char*)d_ws;
    unsigned short* xb  = (unsigned short*)base;  base += 16777216;  // x bf16
    unsigned short* wqt = (unsigned short*)base;  base += 1048576;   // Mq^T [512][1024]
    unsigned short* wkt = (unsigned short*)base;  base += 1048576;   // Mk^T (contig after wqt)
    unsigned short* wvt = (unsigned short*)base;  base += 2097152;   // Mv^T [1024][1024]
    unsigned short* pq  = (unsigned short*)base;  base += 8388608;   // [4*2048][512], pre-scaled /8
    unsigned short* pk  = (unsigned short*)base;  base += 8388608;
    unsigned short* pv  = (unsigned short*)base;  base += 16777216;  // [4*2048][1024]
    unsigned short* vt  = (unsigned short*)base;  base += 16777216;  // [32][128][2048]
    float* rdenl = (float*)base;                  base += 262144;    // [32][2048] = -ln colsum

    k_cvt<<<8192, 256, 0, stream>>>(x, xb, 2097152);
    k_cvtT3<<<dim3(16, 16, 2), 256, 0, stream>>>(Mq, Mk, Mv, wqt, wkt, wvt);
    k_gemm<<<dim3(64, 16), 256, 0, stream>>>(xb, wqt /* = Wt[2048][1024] */, pq, pk, pv);
    k_T<<<dim3(2, 32, 32), 256, 0, stream>>>(pv, vt);
    k_pass1<<<dim3(16, 32), 256, 0, stream>>>(pq, pk, rdenl);
    k_pass2<<<dim3(2, 8, 32), 256, 0, stream>>>(pq, pk, vt, rdenl, out);
}